// Round 5
// baseline (141.305 us; speedup 1.0000x reference)
//
#include <hip/hip_runtime.h>

#define HID 768
#define NTHREADS 256
#define WPB 4            // waves per block
#define MAXD_UNROLL 24   // steps fully unrolled; runtime tail after
#define WD_OFF_BYTES (16u * 1024u * 1024u)   // bd[] offset inside d_ws

// ---- helpers ---------------------------------------------------------------
__device__ __forceinline__ unsigned short f32_to_bf16(float x) {
    unsigned u = __float_as_uint(x);
    u += 0x7FFFu + ((u >> 16) & 1u);          // round-to-nearest-even
    return (unsigned short)(u >> 16);
}
__device__ __forceinline__ float bf16_to_f32(unsigned short u) {
    return __uint_as_float(((unsigned)u) << 16);
}

// ---- kernel 1: Wd[n,k] = bf16(W[n,k,0] - W[n,k,1]);  bd[n] = b0 - b1 -------
// Pure streaming: read 61.4 MB, write 15.4 MB. One thread per 4 k-values.
__global__ __launch_bounds__(NTHREADS) void huffman_prep_kernel(
    const float* __restrict__ node_W,   // [V-1, H, 2]
    const float* __restrict__ node_b,   // [V-1, 2]
    unsigned short* __restrict__ Wd,    // [V-1, H] bf16
    float* __restrict__ bd,             // [V-1]
    int Vm1)
{
    const long idx    = (long)blockIdx.x * NTHREADS + threadIdx.x;  // quad id
    const long nquads = (long)Vm1 * (HID / 4);
    if (idx < nquads) {
        const float4* __restrict__ src = (const float4*)node_W + idx * 2;
        const float4 a = src[0];   // k0:{w0,w1}, k1:{w0,w1}
        const float4 b = src[1];   // k2:{w0,w1}, k3:{w0,w1}
        ushort4 o;
        o.x = f32_to_bf16(a.x - a.y);
        o.y = f32_to_bf16(a.z - a.w);
        o.z = f32_to_bf16(b.x - b.y);
        o.w = f32_to_bf16(b.z - b.w);
        ((ushort4*)Wd)[idx] = o;
    }
    if (idx < Vm1) bd[idx] = node_b[idx * 2] - node_b[idx * 2 + 1];
}

// ---- kernel 2: gather + CE -------------------------------------------------
// One block per token t. Wave w handles steps d = s*4 + w, s = 0..5, fully
// unrolled (no break -> independent gather chains). Per step: 3 x 8 B
// coalesced bf16 loads of Wd[n] (1.5 KB/row), 12 FMAs vs register-resident
// h-fragment (12 floats/lane), 6-level butterfly, sigmoid/CE, block reduce,
// one atomicAdd per block.
__global__ __launch_bounds__(NTHREADS) void huffman_gather_kernel(
    const float* __restrict__ hidden,         // [T, H]
    const int*   __restrict__ target,         // [T]
    const unsigned short* __restrict__ Wd,    // [V-1, H] bf16 diffs
    const float* __restrict__ bd,             // [V-1]
    const int*   __restrict__ path_nodes,     // [V, D]
    const int*   __restrict__ path_bits,      // [V, D]
    const void*  __restrict__ path_mask,      // [V, D] bool (byte OR int32)
    float*       __restrict__ out,            // [1], pre-zeroed
    int D)
{
    const int t    = blockIdx.x;
    const int wave = threadIdx.x >> 6;
    const int lane = threadIdx.x & 63;

    // h fragment: lane owns k = (j*64+lane)*4 .. +3, j = 0..2  (12 floats).
    const float4* __restrict__ h4 = (const float4*)(hidden + (long)t * HID);
    float4 hreg[3];
    #pragma unroll
    for (int j = 0; j < 3; ++j) hreg[j] = h4[j * 64 + lane];

    // Mask layout detect: mask[0,0..3] all true (min Huffman depth >> 4),
    // byte layout reads 0x01010101, int32 layout reads 1.
    const bool mask_is_byte = (*(const unsigned int*)path_mask) > 1u;
    const unsigned char* __restrict__ pm8  = (const unsigned char*)path_mask;
    const int*           __restrict__ pm32 = (const int*)path_mask;

    const int  v    = target[t];
    const long prow = (long)v * D;

    float lsum = 0.0f;

    auto do_step = [&](int d) {
        bool valid = (d < D);
        if (valid) valid = mask_is_byte ? (pm8[prow + d] != 0)
                                        : (pm32[prow + d] != 0);
        const long pidx = valid ? (prow + d) : prow;   // always in-bounds
        const int  n    = valid ? path_nodes[pidx] : 0;

        const ushort4* __restrict__ w4 =
            (const ushort4*)(Wd + (long)n * HID);      // 192 quads/row

        float acc = 0.0f;
        #pragma unroll
        for (int j = 0; j < 3; ++j) {                  // 3 x 8 B loads/lane
            const ushort4 w = w4[j * 64 + lane];
            const float4  h = hreg[j];
            acc += h.x * bf16_to_f32(w.x) + h.y * bf16_to_f32(w.y)
                 + h.z * bf16_to_f32(w.z) + h.w * bf16_to_f32(w.w);
        }

        #pragma unroll
        for (int off = 32; off > 0; off >>= 1)
            acc += __shfl_xor(acc, off, 64);

        // delta = l0 - l1 fully determines the double-softmax CE:
        // p0 = sigmoid(delta), p1 = 1-p0, ce = log(e^p0 + e^p1) - p_bit.
        const float delta = acc + bd[n];
        const float p0  = 1.0f / (1.0f + __expf(-delta));
        const float p1  = 1.0f - p0;
        const float lse = __logf(__expf(p0) + __expf(p1));
        const float pb  = path_bits[pidx] ? p1 : p0;
        lsum += valid ? (lse - pb) : 0.0f;
    };

    #pragma unroll
    for (int s = 0; s < MAXD_UNROLL / WPB; ++s)        // 6 unrolled steps
        do_step(s * WPB + wave);
    for (int d = MAXD_UNROLL + wave; d < D; d += WPB)  // safety tail (0-trip)
        do_step(d);

    // Block reduce: 4 wave sums -> 1 atomic.
    __shared__ float wsum[WPB];
    if (lane == 0) wsum[wave] = lsum;
    __syncthreads();
    if (threadIdx.x == 0) {
        float tot = 0.0f;
        #pragma unroll
        for (int w = 0; w < WPB; ++w) tot += wsum[w];
        atomicAdd(out, tot);
    }
}

extern "C" void kernel_launch(void* const* d_in, const int* in_sizes, int n_in,
                              void* d_out, int out_size, void* d_ws, size_t ws_size,
                              hipStream_t stream) {
    const float* hidden     = (const float*)d_in[0];
    const int*   target     = (const int*)d_in[1];
    const float* node_W     = (const float*)d_in[2];
    const float* node_b     = (const float*)d_in[3];
    const int*   path_nodes = (const int*)d_in[4];
    const int*   path_bits  = (const int*)d_in[5];
    const void*  path_mask  = (const void*)d_in[6];
    float* out = (float*)d_out;

    const int T   = in_sizes[0] / HID;        // B*S = 2048
    const int Vm1 = in_sizes[3] / 2;          // V-1 = 9999
    const int V   = Vm1 + 1;
    const int D   = in_sizes[4] / V;          // padded path depth (~20)

    unsigned short* Wd = (unsigned short*)d_ws;                       // 15.4 MB
    float*          bd = (float*)((char*)d_ws + WD_OFF_BYTES);        // 40 KB

    // out is re-poisoned (0xAA) before every timed call; zero it for atomics.
    hipMemsetAsync(d_out, 0, sizeof(float), stream);

    const long nquads = (long)Vm1 * (HID / 4);
    const int  pblocks = (int)((nquads + NTHREADS - 1) / NTHREADS);
    huffman_prep_kernel<<<dim3(pblocks), dim3(NTHREADS), 0, stream>>>(
        node_W, node_b, Wd, bd, Vm1);

    huffman_gather_kernel<<<dim3(T), dim3(NTHREADS), 0, stream>>>(
        hidden, target, Wd, bd, path_nodes, path_bits, path_mask, out, D);
}